// Round 9
// baseline (130.710 us; speedup 1.0000x reference)
//
#include <hip/hip_runtime.h>

#define K_BINS 1025
#define T_LEN  2000
#define NF     128
#define TQ     500    // t per block (2000 = 4*500, no tail)
#define ROWQ   500    // float4 per full k-row

__device__ __forceinline__ float softplusf(float x) {
    // matches jax.nn.softplus = max(x,0) + log1p(exp(-|x|))
    return fmaxf(x, 0.0f) + log1pf(expf(-fabsf(x)));
}

// out[b2][t][4*bp + w] = sum_k w_f(k) * spec[bp][k][t],  f = b2 + 32*w
// Block = (bp-quad q, b2-quad B, t-quarter th). 256 thr = 4 waves.
// Wave = p (bp = 4q+p). Each wave walks ALL FOUR band-unions (bands w=0..3,
// filters 4B+32w+i) on its own bp -> every wave in the block has an
// IDENTICAL row count (the band structure is bp-independent): perfect
// intra-block balance (R7's 17/22/30/45-row wave spread was the limiter),
// while keeping R7's 2 KB bursts (2 float4/lane per row).
// Per band: merged-run union walk (in-register mel-overlap reuse, exact gap
// skip) with a 3-slot software pipeline (~3 rows = 6 KB in flight per wave).
// Epilogue: LDS [512][17] transpose -> full 64 B line float4 stores.
__global__ __launch_bounds__(256) void fb_fused(
        const float* __restrict__ spec,
        const float* __restrict__ cf,
        const float* __restrict__ bwv,
        const float* __restrict__ fs,
        float*       __restrict__ out) {
    const int q    = blockIdx.x;   // bp-quad 0..7 (id%8 -> XCD q)
    const int B    = blockIdx.y;   // b2-quad 0..7
    const int th   = blockIdx.z;   // t-quarter 0..3
    const int tid  = threadIdx.x;
    const int lane = tid & 63;
    const int p    = tid >> 6;     // bp-local 0..3 (= wave id)
    const int bp   = 4 * q + p;
    const int t0   = TQ * th;
    const bool ok1 = lane < (TQ / 4 - 64);   // 125 float4/chunk: idx 64+lane

    const float4* base4 =
        (const float4*)(spec + (size_t)bp * (K_BINS * (size_t)T_LEN) + t0);

    float4 acc[4][4][2];           // [band][i][half] — all static indexing
#pragma unroll
    for (int w = 0; w < 4; ++w)
#pragma unroll
        for (int i = 0; i < 4; ++i) {
            acc[w][i][0] = make_float4(0.f, 0.f, 0.f, 0.f);
            acc[w][i][1] = make_float4(0.f, 0.f, 0.f, 0.f);
        }

#pragma unroll
    for (int w = 0; w < 4; ++w) {
        // ---- params for the 4 adjacent filters of band w, quad B ----
        float icl[4], mirc[4], mAf[4], Bf[4];
        int   klo[4], khi[4];
#pragma unroll
        for (int i = 0; i < 4; ++i) {
            const int f = 4 * B + 32 * w + i;
            float c  = cf[f];
            float bw = softplusf(bwv[f]) + 0.001f;
            float s0 = softplusf(fs[2 * f])     + 0.1f;
            float s1 = softplusf(fs[2 * f + 1]) + 0.1f;
            float left  = c - bw * s0;
            float right = c + bw * s1;
            float ic = 1.0f / (c - left + 1e-8f);
            float ir = 1.0f / (right - c + 1e-8f);
            icl[i]  = ic;
            mirc[i] = -ir;
            mAf[i]  = -left * ic;            // rise = fk*icl + mAf
            Bf[i]   = fmaf(c, ir, 1.0f);     // fall = fk*mirc + Bf
            klo[i] = max(0, (int)ceilf(left));
            khi[i] = min(K_BINS - 1, (int)floorf(right));
        }

        // ---- merge supports into <=4 contiguous runs ----
        int rs[4], re[4], nr = 0;
        {
            int cs = klo[0], ce = khi[0];
#pragma unroll
            for (int i = 1; i < 4; ++i) {
                if (klo[i] <= ce + 1) ce = max(ce, khi[i]);
                else { rs[nr] = cs; re[nr] = ce; ++nr; cs = klo[i]; ce = khi[i]; }
            }
            rs[nr] = cs; re[nr] = ce; ++nr;
        }

        // ---- 3-slot pipelined union walk ----
        int rF = 0, kF = rs[0];    // fetch cursor (wave-uniform)
        auto advance = [&]() {
            if (kF + 1 <= re[rF]) ++kF;
            else if (rF + 1 < nr) { ++rF; kF = rs[rF]; }
            else kF = -1;
        };

#define LOADROW(d0, d1)                                                   \
        { const float4* rp_ = base4 + (size_t)kF * ROWQ;                  \
          d0 = rp_[lane]; if (ok1) d1 = rp_[64 + lane]; }

#define COMPUTE(kk, v0, v1)                                               \
        { float fk_ = (float)(kk);                                        \
          _Pragma("unroll")                                               \
          for (int i = 0; i < 4; ++i) {                                   \
              float rise_ = fmaf(fk_, icl[i],  mAf[i]);                   \
              float fall_ = fmaf(fk_, mirc[i], Bf[i]);                    \
              float wg_   = fmaxf(0.0f, fminf(rise_, fall_));             \
              acc[w][i][0].x = fmaf(wg_, v0.x, acc[w][i][0].x);           \
              acc[w][i][0].y = fmaf(wg_, v0.y, acc[w][i][0].y);           \
              acc[w][i][0].z = fmaf(wg_, v0.z, acc[w][i][0].z);           \
              acc[w][i][0].w = fmaf(wg_, v0.w, acc[w][i][0].w);           \
              acc[w][i][1].x = fmaf(wg_, v1.x, acc[w][i][1].x);           \
              acc[w][i][1].y = fmaf(wg_, v1.y, acc[w][i][1].y);           \
              acc[w][i][1].z = fmaf(wg_, v1.z, acc[w][i][1].z);           \
              acc[w][i][1].w = fmaf(wg_, v1.w, acc[w][i][1].w);           \
          } }

#define STEP(S0, S1, KS)                                                  \
        { float4 n0_, n1_; int nk_ = -1;                                  \
          if (kF >= 0) { LOADROW(n0_, n1_); nk_ = kF; advance(); }        \
          COMPUTE(KS, S0, S1);                                            \
          S0 = n0_; S1 = n1_; KS = nk_; }

        float4 A0, A1, Bv0, Bv1, C0, C1;
        int kA = -1, kB = -1, kC = -1;
        if (kF >= 0) { LOADROW(A0, A1);   kA = kF; advance(); }
        if (kF >= 0) { LOADROW(Bv0, Bv1); kB = kF; advance(); }
        if (kF >= 0) { LOADROW(C0, C1);   kC = kF; advance(); }

        while (kA >= 0) {
            STEP(A0, A1, kA);
            if (kB < 0) break;
            STEP(Bv0, Bv1, kB);
            if (kC < 0) break;
            STEP(C0, C1, kC);
        }
#undef STEP
#undef COMPUTE
#undef LOADROW
    }

    // ---- Epilogue: per filter i, transpose via LDS, full 64 B line stores.
    __shared__ float tile[512][17];
#pragma unroll
    for (int i = 0; i < 4; ++i) {
        __syncthreads();               // protect tile reuse
#pragma unroll
        for (int w = 0; w < 4; ++w) {
            const int col = 4 * p + w; // f2 - 16q
            const int rb  = 4 * lane;
#pragma unroll
            for (int r = 0; r < 4; ++r)
                tile[rb + r][col] = (&acc[w][i][0].x)[r];
            if (ok1) {
#pragma unroll
                for (int r = 0; r < 4; ++r)
                    tile[256 + rb + r][col] = (&acc[w][i][1].x)[r];
            }
        }
        __syncthreads();
        const int b2 = 4 * B + i;
        const int c4 = tid & 3;
#pragma unroll
        for (int rr = 0; rr < 8; ++rr) {
            int tl = 64 * rr + (tid >> 2);
            if (tl < TQ) {
                float4 v = make_float4(tile[tl][4 * c4 + 0], tile[tl][4 * c4 + 1],
                                       tile[tl][4 * c4 + 2], tile[tl][4 * c4 + 3]);
                *reinterpret_cast<float4*>(
                    out + ((size_t)b2 * T_LEN + t0 + tl) * NF + 16 * q + 4 * c4) = v;
            }
        }
    }
}

extern "C" void kernel_launch(void* const* d_in, const int* in_sizes, int n_in,
                              void* d_out, int out_size, void* d_ws, size_t ws_size,
                              hipStream_t stream) {
    const float* spec = (const float*)d_in[0];   // (32, 1025, 2000) f32
    const float* cf   = (const float*)d_in[1];   // (128,)
    const float* bwv  = (const float*)d_in[2];   // (128,)
    const float* fs   = (const float*)d_in[3];   // (128, 2)
    float* out = (float*)d_out;                  // (32, 2000, 128) f32

    fb_fused<<<dim3(8, 8, 4), 256, 0, stream>>>(spec, cf, bwv, fs, out);
}